// Round 4
// baseline (1738.063 us; speedup 1.0000x reference)
//
#include <hip/hip_runtime.h>

#define NN   30000
#define NE   480000
#define NR   7
#define NSEG (NN*NR)
#define DH   512
#define DIN  21
#define EPSB 1e-5f
#define BK   32

typedef __attribute__((ext_vector_type(8))) short bf16x8;
typedef __attribute__((ext_vector_type(8))) unsigned short u16x8;
typedef __attribute__((ext_vector_type(4))) float f32x4;
typedef unsigned short ushortT;

static inline size_t align256(size_t x){ return (x + 255) & ~(size_t)255; }

__device__ inline float bf2f(ushortT u){
    unsigned int i = ((unsigned int)u) << 16; float f; __builtin_memcpy(&f, &i, 4); return f;
}
__device__ inline ushortT f2bf(float f){
    unsigned int i; __builtin_memcpy(&i, &f, 4);
    unsigned int r = i + 0x7FFFu + ((i >> 16) & 1u);
    return (ushortT)(r >> 16);
}

__device__ inline void load_lds16(const ushortT* g, ushortT* l){
    __builtin_amdgcn_global_load_lds((const __attribute__((address_space(1))) unsigned int*)g,
                                     (__attribute__((address_space(3))) unsigned int*)l,
                                     16, 0, 0);
}

// ---------------- CSR build (counting sort by seg = dst*7+rel) ----------------

__global__ void hist_k(const int* __restrict__ dst, const int* __restrict__ rel,
                       int* __restrict__ counts){
    int e = blockIdx.x*256 + threadIdx.x;
    if (e < NE) atomicAdd(&counts[dst[e]*NR + rel[e]], 1);
}

__global__ void scan1_k(const int* __restrict__ counts, int* __restrict__ bsum){
    __shared__ int sd[256];
    int t = threadIdx.x;
    int base = blockIdx.x*1024 + t*4;
    int s = 0;
#pragma unroll
    for (int i = 0; i < 4; i++){ int idx = base + i; if (idx < NSEG) s += counts[idx]; }
    sd[t] = s; __syncthreads();
    for (int off = 128; off > 0; off >>= 1){
        if (t < off) sd[t] += sd[t+off];
        __syncthreads();
    }
    if (t == 0) bsum[blockIdx.x] = sd[0];
}

__global__ void scan2_k(int* __restrict__ bsum, int nb, int* __restrict__ seg_start){
    __shared__ int sd[256];
    int t = threadIdx.x;
    int v = (t < nb) ? bsum[t] : 0;
    sd[t] = v; __syncthreads();
    for (int off = 1; off < 256; off <<= 1){
        int x = sd[t];
        if (t >= off) x += sd[t-off];
        __syncthreads();
        sd[t] = x; __syncthreads();
    }
    if (t < nb) bsum[t] = (t == 0) ? 0 : sd[t-1];
    if (t == 0) seg_start[NSEG] = NE;
}

__global__ void scan3_k(const int* __restrict__ counts, const int* __restrict__ bsum,
                        int* __restrict__ seg_start){
    __shared__ int sd[256];
    int t = threadIdx.x;
    int base = blockIdx.x*1024 + t*4;
    int v[4]; int s = 0;
#pragma unroll
    for (int i = 0; i < 4; i++){ int idx = base + i; v[i] = (idx < NSEG) ? counts[idx] : 0; s += v[i]; }
    sd[t] = s; __syncthreads();
    for (int off = 1; off < 256; off <<= 1){
        int x = sd[t];
        if (t >= off) x += sd[t-off];
        __syncthreads();
        sd[t] = x; __syncthreads();
    }
    int excl = sd[t] - s + bsum[blockIdx.x];
#pragma unroll
    for (int i = 0; i < 4; i++){
        int idx = base + i;
        if (idx < NSEG){ seg_start[idx] = excl; excl += v[i]; }
    }
}

__global__ void scatter_k(const int* __restrict__ src, const int* __restrict__ dst,
                          const int* __restrict__ rel, const int* __restrict__ seg_start,
                          int* __restrict__ cursor, int* __restrict__ src_sorted){
    int e = blockIdx.x*256 + threadIdx.x;
    if (e < NE){
        int s = dst[e]*NR + rel[e];
        int pos = seg_start[s] + atomicAdd(&cursor[s], 1);
        src_sorted[pos] = src[e];
    }
}

// ---------------- layer 0: segment sum d=21, Kp=192 (147 upd | 21 self | 24 pad) ----------------

__global__ void segsum21b_k(const float* __restrict__ x0,
                            const int* __restrict__ seg_start, const int* __restrict__ src_sorted,
                            ushortT* __restrict__ Acat){
    int n = blockIdx.x;
    int t = threadIdx.x;   // 64
    ushortT* arow = Acat + (long)n*192;
    if (t < DIN){
        int sb = n*NR;
        int e0 = seg_start[sb];
#pragma unroll
        for (int r = 0; r < NR; r++){
            int e1 = seg_start[sb + r + 1];
            float a = 0.f;
            for (int e = e0; e < e1; e++) a += x0[(long)src_sorted[e]*DIN + t];
            e0 = e1;
            arow[r*DIN + t] = f2bf(a);
        }
        arow[7*DIN + t] = f2bf(x0[(long)n*DIN + t]);
    }
    if (t >= 40) arow[168 + (t - 40)] = 0;   // zero pad cols 168..191
}

// ---------------- weight concat + bf16 convert: Wcat[512][Kp] ----------------

__global__ void convw_k(const float* __restrict__ lw, const float* __restrict__ sw,
                        int d, int Kp, ushortT* __restrict__ Wc){
    int i = blockIdx.x*256 + threadIdx.x;
    if (i < DH*Kp){
        int n = i / Kp, k = i % Kp;
        float v;
        if (k < 7*d)      v = lw[(long)n*7*d + k];
        else if (k < 8*d) v = sw[(long)n*d + (k - 7*d)];
        else              v = 0.f;
        Wc[i] = f2bf(v);
    }
}

// ---------------- layer-0 GEMM (128x128 tile, 4 waves) + fused col-stats ----------------

__global__ __launch_bounds__(256)
void gemm_mfma_k(const ushortT* __restrict__ A, int lda, int M,
                 const ushortT* __restrict__ W,
                 const float* __restrict__ b1, const float* __restrict__ b2,
                 float* __restrict__ C, int nt, float* __restrict__ sums){
    __shared__ ushortT As[2][128*BK];
    __shared__ ushortT Bs[2][128*BK];
    const int t    = threadIdx.x;
    const int bm   = blockIdx.x*128;
    const int bn   = blockIdx.y*128;
    const int w    = t >> 6;
    const int lane = t & 63;

    int f0 = w*128 + lane, f1 = f0 + 64;
    int ar0 = f0 >> 2, ac0 = (f0 & 3)*8;
    int ar1 = f1 >> 2, ac1 = (f1 & 3)*8;
    const ushortT* gA0 = A + (long)min(bm + ar0, M-1)*lda + ac0;
    const ushortT* gA1 = A + (long)min(bm + ar1, M-1)*lda + ac1;
    const ushortT* gB0 = W + (long)(bn + ar0)*lda + ac0;
    const ushortT* gB1 = W + (long)(bn + ar1)*lda + ac1;
    const int d0 = (w*128 +  0)*8;
    const int d1 = (w*128 + 64)*8;

    f32x4 acc[4][4];
#pragma unroll
    for (int m = 0; m < 4; m++)
#pragma unroll
        for (int n = 0; n < 4; n++) acc[m][n] = (f32x4){0.f,0.f,0.f,0.f};

    const int wm = w >> 1, wn = w & 1;
    const int r = lane & 15, hi = lane >> 4;

    load_lds16(gA0, &As[0][d0]);
    load_lds16(gA1, &As[0][d1]);
    load_lds16(gB0, &Bs[0][d0]);
    load_lds16(gB1, &Bs[0][d1]);

    for (int kt = 0; kt < nt; ++kt){
        __syncthreads();
        if (kt + 1 < nt){
            int k0 = (kt + 1)*BK;
            int nb = (kt + 1) & 1;
            load_lds16(gA0 + k0, &As[nb][d0]);
            load_lds16(gA1 + k0, &As[nb][d1]);
            load_lds16(gB0 + k0, &Bs[nb][d0]);
            load_lds16(gB1 + k0, &Bs[nb][d1]);
        }
        int buf = kt & 1;
        bf16x8 af[4], bfr[4];
#pragma unroll
        for (int m = 0; m < 4; m++)
            af[m] = *reinterpret_cast<const bf16x8*>(&As[buf][(wm*64 + m*16 + r)*BK + hi*8]);
#pragma unroll
        for (int n = 0; n < 4; n++)
            bfr[n] = *reinterpret_cast<const bf16x8*>(&Bs[buf][(wn*64 + n*16 + r)*BK + hi*8]);
#pragma unroll
        for (int m = 0; m < 4; m++)
#pragma unroll
            for (int n = 0; n < 4; n++)
                acc[m][n] = __builtin_amdgcn_mfma_f32_16x16x32_bf16(af[m], bfr[n], acc[m][n], 0, 0, 0);
    }

#pragma unroll
    for (int n = 0; n < 4; n++){
        int col = bn + wn*64 + n*16 + r;
        float bb = b1[col] + b2[col];
        float s = 0.f, s2 = 0.f;
#pragma unroll
        for (int m = 0; m < 4; m++){
            int row = bm + wm*64 + m*16 + hi*4;
#pragma unroll
            for (int q = 0; q < 4; q++){
                if (row + q < M){
                    float v = acc[m][n][q] + bb;
                    C[(long)(row + q)*DH + col] = v;
                    s += v; s2 = fmaf(v, v, s2);
                }
            }
        }
        s  += __shfl_xor(s, 16);  s  += __shfl_xor(s, 32);
        s2 += __shfl_xor(s2, 16); s2 += __shfl_xor(s2, 32);
        if (hi == 0){
            atomicAdd(&sums[col], s);
            atomicAdd(&sums[DH + col], s2);
        }
    }
}

// ---------------- fused gather-GEMM v2 (layers 1,2) ----------------
// C[M,512] = [segsum(hbf) | hbf] @ Wcat[512,4096]^T + b1 + b2.
// 16 column-group phases p: one pass over each node's FULL edge list produces
// all 7 rel K-tiles (reg accumulation, ds_write) + self tile via global_load_lds.
// Then 8 MFMA sub-tiles per phase with Bs streamed (stage-1-ahead dbuf).
// K-tile order: kt = r*16+p (r<7), 112+p (self) — order-independent accumulation.

__global__ __launch_bounds__(512, 2)
void gemm_fused2_k(const ushortT* __restrict__ hbf,
                   const int* __restrict__ seg_start, const int* __restrict__ src_sorted,
                   const ushortT* __restrict__ W,
                   const float* __restrict__ b1, const float* __restrict__ b2,
                   float* __restrict__ C, float* __restrict__ sums, int M){
    __shared__ ushortT As8[8*128*BK];      // 64 KB: tile j at j*4096 (ushorts), [128][32] row-major
    __shared__ ushortT Bs[2][512*BK];      // 64 KB: [512][32] row-major
    const int t    = threadIdx.x;
    const int bm   = blockIdx.x*128;
    const int w    = t >> 6, lane = t & 63;
    const int wm   = w >> 2, wn = w & 3;   // 2 x 4 wave grid (64 rows x 128 cols each)
    const int r    = lane & 15, hi = lane >> 4;
    const int trow = t >> 2, tq = t & 3;   // gather map: node row, 8-col chunk
    const int gn   = min(bm + trow, M - 1);

    // per-node segment bounds (7 segs -> 8 boundaries), kept in registers
    int sb[8];
#pragma unroll
    for (int i = 0; i < 8; i++) sb[i] = seg_start[gn*NR + i];

    f32x4 acc[4][8];
#pragma unroll
    for (int m = 0; m < 4; m++)
#pragma unroll
        for (int n = 0; n < 8; n++) acc[m][n] = (f32x4){0.f,0.f,0.f,0.f};

    // stage B K-tile kt into Bs[b]
    auto stageB = [&](int kt, int b){
#pragma unroll
        for (int i = 0; i < 4; i++){
            int f = i*512 + t;
            int row = f >> 2, c = f & 3;
            load_lds16(W + (long)row*4096 + kt*BK + c*8, &Bs[b][f*8]);
        }
    };

    // gather phase p: build rel tiles 0..6 (reg accum + ds_write) and issue self tile (7)
    auto gatherA = [&](int p){
        const int coff = p*BK + tq*8;
        // self tile: As8[7], linear dest, per-lane source
        load_lds16(hbf + (long)gn*DH + coff, &As8[7*4096 + t*8]);
#pragma unroll
        for (int rr = 0; rr < NR; rr++){
            float a0=0.f,a1=0.f,a2=0.f,a3=0.f,a4=0.f,a5=0.f,a6=0.f,a7=0.f;
            for (int e = sb[rr]; e < sb[rr+1]; e++){
                const u16x8 v = *reinterpret_cast<const u16x8*>(
                    hbf + (long)src_sorted[e]*DH + coff);
                a0 += bf2f((ushortT)v[0]); a1 += bf2f((ushortT)v[1]);
                a2 += bf2f((ushortT)v[2]); a3 += bf2f((ushortT)v[3]);
                a4 += bf2f((ushortT)v[4]); a5 += bf2f((ushortT)v[5]);
                a6 += bf2f((ushortT)v[6]); a7 += bf2f((ushortT)v[7]);
            }
            u16x8 o;
            o[0]=f2bf(a0); o[1]=f2bf(a1); o[2]=f2bf(a2); o[3]=f2bf(a3);
            o[4]=f2bf(a4); o[5]=f2bf(a5); o[6]=f2bf(a6); o[7]=f2bf(a7);
            *reinterpret_cast<u16x8*>(&As8[rr*4096 + trow*BK + tq*8]) = o;
        }
    };

    // prologue: gather phase 0, stage first B tile (kt = 0*16+0)
    gatherA(0);
    stageB(0, 0);
    __syncthreads();

    for (int p = 0; p < 16; p++){
#pragma unroll
        for (int j = 0; j < 8; j++){
            const int b = j & 1;
            // stage next B tile (1 ahead)
            int nj = j + 1, np = p;
            if (nj == 8){ nj = 0; np = p + 1; }
            if (np < 16){
                int nkt = (nj < 7) ? nj*16 + np : 112 + np;
                stageB(nkt, b ^ 1);
            }
            bf16x8 af[4], bfr[8];
#pragma unroll
            for (int m = 0; m < 4; m++)
                af[m] = *reinterpret_cast<const bf16x8*>(
                    &As8[j*4096 + (wm*64 + m*16 + r)*BK + hi*8]);
#pragma unroll
            for (int n = 0; n < 8; n++)
                bfr[n] = *reinterpret_cast<const bf16x8*>(
                    &Bs[b][(wn*128 + n*16 + r)*BK + hi*8]);
#pragma unroll
            for (int m = 0; m < 4; m++)
#pragma unroll
                for (int n = 0; n < 8; n++)
                    acc[m][n] = __builtin_amdgcn_mfma_f32_16x16x32_bf16(af[m], bfr[n], acc[m][n], 0, 0, 0);
            __syncthreads();   // Bs[b] reads done (safe to overwrite at j+2); staged tile drained
        }
        // all As8 reads for phase p are complete (last barrier above)
        if (p + 1 < 16){
            gatherA(p + 1);
            __syncthreads();   // As8 writes visible before next phase's MFMA
        }
    }

    // epilogue: bias + store + fused column stats
#pragma unroll
    for (int n = 0; n < 8; n++){
        int col = wn*128 + n*16 + r;
        float bb = b1[col] + b2[col];
        float s = 0.f, s2 = 0.f;
#pragma unroll
        for (int m = 0; m < 4; m++){
            int row = bm + wm*64 + m*16 + hi*4;
#pragma unroll
            for (int q = 0; q < 4; q++){
                if (row + q < M){
                    float v = acc[m][n][q] + bb;
                    C[(long)(row + q)*DH + col] = v;
                    s += v; s2 = fmaf(v, v, s2);
                }
            }
        }
        s  += __shfl_xor(s, 16);  s  += __shfl_xor(s, 32);
        s2 += __shfl_xor(s2, 16); s2 += __shfl_xor(s2, 32);
        if (hi == 0){
            atomicAdd(&sums[col], s);
            atomicAdd(&sums[DH + col], s2);
        }
    }
}

// ---------------- BatchNorm passes ----------------

__global__ void finalize_k(const float* __restrict__ sums, const float* __restrict__ g,
                           const float* __restrict__ b, float* __restrict__ ac){
    int c = blockIdx.x*256 + threadIdx.x;
    if (c < DH){
        float mu  = sums[c] * (1.f/NN);
        float var = sums[DH + c] * (1.f/NN) - mu*mu;
        var = fmaxf(var, 0.f);
        float a = g[c] * rsqrtf(var + EPSB);
        ac[c]      = a;
        ac[DH + c] = fmaf(-mu, a, b[c]);
    }
}

__global__ void bnrelu_k(float* __restrict__ buf, int M, const float* __restrict__ ac,
                         float* __restrict__ sums2){
    int col = blockIdx.x*256 + threadIdx.x;
    int r0 = blockIdx.y*512;
    int r1 = min(r0 + 512, M);
    float a = ac[col], c = ac[DH + col];
    float s = 0.f, s2 = 0.f;
    for (int r = r0; r < r1; r++){
        long idx = (long)r*DH + col;
        float y = fmaxf(fmaf(a, buf[idx], c), 0.f);
        buf[idx] = y;
        s += y; s2 = fmaf(y, y, s2);
    }
    atomicAdd(&sums2[col], s);
    atomicAdd(&sums2[DH + col], s2);
}

__global__ void bn2write_k(const float* __restrict__ buf, const float* __restrict__ ac,
                           float* __restrict__ out, ushortT* __restrict__ hbf, int layer){
    long i = (long)blockIdx.x*256 + threadIdx.x;
    if (i < (long)NN*DH){
        int r = (int)(i >> 9);
        int c = (int)(i & 511);
        float h = fmaf(ac[c], buf[i], ac[DH + c]);
        out[(long)r*(3*DH) + layer*DH + c] = h;
        hbf[i] = f2bf(h);
    }
}

// ---------------- driver ----------------

extern "C" void kernel_launch(void* const* d_in, const int* in_sizes, int n_in,
                              void* d_out, int out_size, void* d_ws, size_t ws_size,
                              hipStream_t stream){
    const float* x0  = (const float*)d_in[0];
    const int*   src = (const int*)d_in[1];
    const int*   dst = (const int*)d_in[2];
    const int*   rel = (const int*)d_in[3];
    const float* lin_w[3]  = {(const float*)d_in[4],  (const float*)d_in[12], (const float*)d_in[20]};
    const float* self_w[3] = {(const float*)d_in[5],  (const float*)d_in[13], (const float*)d_in[21]};
    const float* lin_b[3]  = {(const float*)d_in[6],  (const float*)d_in[14], (const float*)d_in[22]};
    const float* self_b[3] = {(const float*)d_in[7],  (const float*)d_in[15], (const float*)d_in[23]};
    const float* bn1_g[3]  = {(const float*)d_in[8],  (const float*)d_in[16], (const float*)d_in[24]};
    const float* bn1_b[3]  = {(const float*)d_in[9],  (const float*)d_in[17], (const float*)d_in[25]};
    const float* bn2_g[3]  = {(const float*)d_in[10], (const float*)d_in[18], (const float*)d_in[26]};
    const float* bn2_b[3]  = {(const float*)d_in[11], (const float*)d_in[19], (const float*)d_in[27]};

    char* ws = (char*)d_ws;
    size_t off = 0;
    auto alloc = [&](size_t bytes)->char*{ char* p = ws + off; off = align256(off + bytes); return p; };

    int*     counts     = (int*)alloc((size_t)NSEG*4);
    int*     cursor     = (int*)alloc((size_t)NSEG*4);
    int*     seg_start  = (int*)alloc((size_t)(NSEG+1)*4);
    int*     bsum       = (int*)alloc(1024*4);
    int*     src_sorted = (int*)alloc((size_t)NE*4);
    float*   stats      = (float*)alloc((size_t)8*DH*4);
    float*   sums1 = stats;            float* sums2 = stats + 2*DH;
    float*   ac1   = stats + 4*DH;     float* ac2   = stats + 6*DH;
    float*   outbuf = (float*)alloc((size_t)NN*DH*4);
    ushortT* hbf    = (ushortT*)alloc((size_t)NN*DH*2);
    ushortT* Wcat   = (ushortT*)alloc((size_t)DH*4096*2);
    ushortT* Acat0  = (ushortT*)alloc((size_t)NN*192*2);

    // CSR build (graph is layer-invariant)
    hipMemsetAsync(counts, 0, (size_t)NSEG*4, stream);
    hipMemsetAsync(cursor, 0, (size_t)NSEG*4, stream);
    hist_k<<<(NE+255)/256, 256, 0, stream>>>(dst, rel, counts);
    int nb = (NSEG + 1023)/1024;
    scan1_k<<<nb, 256, 0, stream>>>(counts, bsum);
    scan2_k<<<1, 256, 0, stream>>>(bsum, nb, seg_start);
    scan3_k<<<nb, 256, 0, stream>>>(counts, bsum, seg_start);
    scatter_k<<<(NE+255)/256, 256, 0, stream>>>(src, dst, rel, seg_start, cursor, src_sorted);

    const int MB = (NN + 127)/128;   // 235 row panels

    for (int layer = 0; layer < 3; layer++){
        int d  = (layer == 0) ? DIN : DH;
        int Kp = (layer == 0) ? 192 : 8*DH;
        convw_k<<<(DH*Kp + 255)/256, 256, 0, stream>>>(lin_w[layer], self_w[layer], d, Kp, Wcat);
        hipMemsetAsync(stats, 0, (size_t)4*DH*4, stream);   // sums1 + sums2

        if (layer == 0){
            segsum21b_k<<<NN, 64, 0, stream>>>(x0, seg_start, src_sorted, Acat0);
            gemm_mfma_k<<<dim3(MB, 4), 256, 0, stream>>>(
                Acat0, Kp, NN, Wcat, lin_b[layer], self_b[layer], outbuf, Kp/BK, sums1);
        } else {
            gemm_fused2_k<<<MB, 512, 0, stream>>>(
                hbf, seg_start, src_sorted, Wcat, lin_b[layer], self_b[layer],
                outbuf, sums1, NN);
        }

        finalize_k<<<2, 256, 0, stream>>>(sums1, bn1_g[layer], bn1_b[layer], ac1);
        bnrelu_k<<<dim3(2, (NN+511)/512), 256, 0, stream>>>(outbuf, NN, ac1, sums2);
        finalize_k<<<2, 256, 0, stream>>>(sums2, bn2_g[layer], bn2_b[layer], ac2);
        bn2write_k<<<((long)NN*DH + 255)/256, 256, 0, stream>>>(outbuf, ac2, (float*)d_out, hbf, layer);
    }
}

// Round 5
// 1613.785 us; speedup vs baseline: 1.0770x; 1.0770x over previous
//
#include <hip/hip_runtime.h>

#define NN   30000
#define NE   480000
#define NR   7
#define NSEG (NN*NR)
#define DH   512
#define DIN  21
#define EPSB 1e-5f
#define BK   32

typedef __attribute__((ext_vector_type(8))) short bf16x8;
typedef __attribute__((ext_vector_type(8))) unsigned short u16x8;
typedef __attribute__((ext_vector_type(4))) float f32x4;
typedef unsigned short ushortT;

static inline size_t align256(size_t x){ return (x + 255) & ~(size_t)255; }

__device__ inline float bf2f(ushortT u){
    unsigned int i = ((unsigned int)u) << 16; float f; __builtin_memcpy(&f, &i, 4); return f;
}
__device__ inline ushortT f2bf(float f){
    unsigned int i; __builtin_memcpy(&i, &f, 4);
    unsigned int r = i + 0x7FFFu + ((i >> 16) & 1u);
    return (ushortT)(r >> 16);
}

__device__ inline void load_lds16(const ushortT* g, ushortT* l){
    __builtin_amdgcn_global_load_lds((const __attribute__((address_space(1))) unsigned int*)g,
                                     (__attribute__((address_space(3))) unsigned int*)l,
                                     16, 0, 0);
}

// ---------------- CSR build (counting sort by seg = dst*7+rel) ----------------

__global__ void hist_k(const int* __restrict__ dst, const int* __restrict__ rel,
                       int* __restrict__ counts){
    int e = blockIdx.x*256 + threadIdx.x;
    if (e < NE) atomicAdd(&counts[dst[e]*NR + rel[e]], 1);
}

__global__ void scan1_k(const int* __restrict__ counts, int* __restrict__ bsum){
    __shared__ int sd[256];
    int t = threadIdx.x;
    int base = blockIdx.x*1024 + t*4;
    int s = 0;
#pragma unroll
    for (int i = 0; i < 4; i++){ int idx = base + i; if (idx < NSEG) s += counts[idx]; }
    sd[t] = s; __syncthreads();
    for (int off = 128; off > 0; off >>= 1){
        if (t < off) sd[t] += sd[t+off];
        __syncthreads();
    }
    if (t == 0) bsum[blockIdx.x] = sd[0];
}

__global__ void scan2_k(int* __restrict__ bsum, int nb, int* __restrict__ seg_start){
    __shared__ int sd[256];
    int t = threadIdx.x;
    int v = (t < nb) ? bsum[t] : 0;
    sd[t] = v; __syncthreads();
    for (int off = 1; off < 256; off <<= 1){
        int x = sd[t];
        if (t >= off) x += sd[t-off];
        __syncthreads();
        sd[t] = x; __syncthreads();
    }
    if (t < nb) bsum[t] = (t == 0) ? 0 : sd[t-1];
    if (t == 0) seg_start[NSEG] = NE;
}

__global__ void scan3_k(const int* __restrict__ counts, const int* __restrict__ bsum,
                        int* __restrict__ seg_start){
    __shared__ int sd[256];
    int t = threadIdx.x;
    int base = blockIdx.x*1024 + t*4;
    int v[4]; int s = 0;
#pragma unroll
    for (int i = 0; i < 4; i++){ int idx = base + i; v[i] = (idx < NSEG) ? counts[idx] : 0; s += v[i]; }
    sd[t] = s; __syncthreads();
    for (int off = 1; off < 256; off <<= 1){
        int x = sd[t];
        if (t >= off) x += sd[t-off];
        __syncthreads();
        sd[t] = x; __syncthreads();
    }
    int excl = sd[t] - s + bsum[blockIdx.x];
#pragma unroll
    for (int i = 0; i < 4; i++){
        int idx = base + i;
        if (idx < NSEG){ seg_start[idx] = excl; excl += v[i]; }
    }
}

__global__ void scatter_k(const int* __restrict__ src, const int* __restrict__ dst,
                          const int* __restrict__ rel, const int* __restrict__ seg_start,
                          int* __restrict__ cursor, int* __restrict__ src_sorted){
    int e = blockIdx.x*256 + threadIdx.x;
    if (e < NE){
        int s = dst[e]*NR + rel[e];
        int pos = seg_start[s] + atomicAdd(&cursor[s], 1);
        src_sorted[pos] = src[e];
    }
}

// ---------------- layer 0: segment sum d=21, Kp=192 (147 upd | 21 self | 24 pad) ----------------

__global__ void segsum21b_k(const float* __restrict__ x0,
                            const int* __restrict__ seg_start, const int* __restrict__ src_sorted,
                            ushortT* __restrict__ Acat){
    int n = blockIdx.x;
    int t = threadIdx.x;   // 64
    ushortT* arow = Acat + (long)n*192;
    if (t < DIN){
        int sb = n*NR;
        int e0 = seg_start[sb];
#pragma unroll
        for (int r = 0; r < NR; r++){
            int e1 = seg_start[sb + r + 1];
            float a = 0.f;
            for (int e = e0; e < e1; e++) a += x0[(long)src_sorted[e]*DIN + t];
            e0 = e1;
            arow[r*DIN + t] = f2bf(a);
        }
        arow[7*DIN + t] = f2bf(x0[(long)n*DIN + t]);
    }
    if (t >= 40) arow[168 + (t - 40)] = 0;   // zero pad cols 168..191
}

// ---------------- layers 1,2: one WAVE per node, full-row segment sum → Acat[*,4096] ----------------
// 64 lanes x ushort8 = full 512-col row per load; edge loop is wave-uniform (no divergence);
// src_sorted[e] is a scalar load. K-concat layout: [rel0..rel6 | self], bf16.

__global__ __launch_bounds__(256)
void segsum_wave_k(const ushortT* __restrict__ hbf,
                   const int* __restrict__ seg_start, const int* __restrict__ src_sorted,
                   ushortT* __restrict__ Acat, int c0, int cn){
    int wid = (blockIdx.x*256 + threadIdx.x) >> 6;
    if (wid >= cn) return;
    const int n = c0 + wid;
    const int lane = (threadIdx.x & 63);
    const int co = lane*8;

    int sb[8];
#pragma unroll
    for (int i = 0; i < 8; i++) sb[i] = seg_start[n*NR + i];

    float a[NR][8];
#pragma unroll
    for (int r = 0; r < NR; r++)
#pragma unroll
        for (int j = 0; j < 8; j++) a[r][j] = 0.f;

#pragma unroll
    for (int r = 0; r < NR; r++){
        for (int e = sb[r]; e < sb[r+1]; e++){
            u16x8 v = *reinterpret_cast<const u16x8*>(hbf + (long)src_sorted[e]*DH + co);
#pragma unroll
            for (int j = 0; j < 8; j++) a[r][j] += bf2f((ushortT)v[j]);
        }
    }

    ushortT* arow = Acat + (long)wid*4096 + co;
#pragma unroll
    for (int r = 0; r < NR; r++){
        u16x8 o;
#pragma unroll
        for (int j = 0; j < 8; j++) o[j] = f2bf(a[r][j]);
        *reinterpret_cast<u16x8*>(arow + r*DH) = o;
    }
    *reinterpret_cast<u16x8*>(arow + 7*DH) =
        *reinterpret_cast<const u16x8*>(hbf + (long)n*DH + co);
}

// ---------------- weight concat + bf16 convert: Wcat[512][Kp] ----------------

__global__ void convw_k(const float* __restrict__ lw, const float* __restrict__ sw,
                        int d, int Kp, ushortT* __restrict__ Wc){
    int i = blockIdx.x*256 + threadIdx.x;
    if (i < DH*Kp){
        int n = i / Kp, k = i % Kp;
        float v;
        if (k < 7*d)      v = lw[(long)n*7*d + k];
        else if (k < 8*d) v = sw[(long)n*d + (k - 7*d)];
        else              v = 0.f;
        Wc[i] = f2bf(v);
    }
}

// ---------------- MFMA GEMM (128x128 tile, 4 waves) + fused col-stats ----------------
// grid = (N-tiles fastest, M-panels): consecutive blocks share the same A-panel → L2/L3 hits.

__global__ __launch_bounds__(256)
void gemm_mfma_k(const ushortT* __restrict__ A, int lda, int M,
                 const ushortT* __restrict__ W,
                 const float* __restrict__ b1, const float* __restrict__ b2,
                 float* __restrict__ C, int nt, float* __restrict__ sums){
    __shared__ ushortT As[2][128*BK];
    __shared__ ushortT Bs[2][128*BK];
    const int t    = threadIdx.x;
    const int bm   = blockIdx.y*128;
    const int bn   = blockIdx.x*128;
    const int w    = t >> 6;
    const int lane = t & 63;

    int f0 = w*128 + lane, f1 = f0 + 64;
    int ar0 = f0 >> 2, ac0 = (f0 & 3)*8;
    int ar1 = f1 >> 2, ac1 = (f1 & 3)*8;
    const ushortT* gA0 = A + (long)min(bm + ar0, M-1)*lda + ac0;
    const ushortT* gA1 = A + (long)min(bm + ar1, M-1)*lda + ac1;
    const ushortT* gB0 = W + (long)(bn + ar0)*lda + ac0;
    const ushortT* gB1 = W + (long)(bn + ar1)*lda + ac1;
    const int d0 = (w*128 +  0)*8;
    const int d1 = (w*128 + 64)*8;

    f32x4 acc[4][4];
#pragma unroll
    for (int m = 0; m < 4; m++)
#pragma unroll
        for (int n = 0; n < 4; n++) acc[m][n] = (f32x4){0.f,0.f,0.f,0.f};

    const int wm = w >> 1, wn = w & 1;
    const int r = lane & 15, hi = lane >> 4;

    load_lds16(gA0, &As[0][d0]);
    load_lds16(gA1, &As[0][d1]);
    load_lds16(gB0, &Bs[0][d0]);
    load_lds16(gB1, &Bs[0][d1]);

    for (int kt = 0; kt < nt; ++kt){
        __syncthreads();
        if (kt + 1 < nt){
            int k0 = (kt + 1)*BK;
            int nb = (kt + 1) & 1;
            load_lds16(gA0 + k0, &As[nb][d0]);
            load_lds16(gA1 + k0, &As[nb][d1]);
            load_lds16(gB0 + k0, &Bs[nb][d0]);
            load_lds16(gB1 + k0, &Bs[nb][d1]);
        }
        int buf = kt & 1;
        bf16x8 af[4], bfr[4];
#pragma unroll
        for (int m = 0; m < 4; m++)
            af[m] = *reinterpret_cast<const bf16x8*>(&As[buf][(wm*64 + m*16 + r)*BK + hi*8]);
#pragma unroll
        for (int n = 0; n < 4; n++)
            bfr[n] = *reinterpret_cast<const bf16x8*>(&Bs[buf][(wn*64 + n*16 + r)*BK + hi*8]);
#pragma unroll
        for (int m = 0; m < 4; m++)
#pragma unroll
            for (int n = 0; n < 4; n++)
                acc[m][n] = __builtin_amdgcn_mfma_f32_16x16x32_bf16(af[m], bfr[n], acc[m][n], 0, 0, 0);
    }

#pragma unroll
    for (int n = 0; n < 4; n++){
        int col = bn + wn*64 + n*16 + r;
        float bb = b1[col] + b2[col];
        float s = 0.f, s2 = 0.f;
#pragma unroll
        for (int m = 0; m < 4; m++){
            int row = bm + wm*64 + m*16 + hi*4;
#pragma unroll
            for (int q = 0; q < 4; q++){
                if (row + q < M){
                    float v = acc[m][n][q] + bb;
                    C[(long)(row + q)*DH + col] = v;
                    s += v; s2 = fmaf(v, v, s2);
                }
            }
        }
        s  += __shfl_xor(s, 16);  s  += __shfl_xor(s, 32);
        s2 += __shfl_xor(s2, 16); s2 += __shfl_xor(s2, 32);
        if (hi == 0){
            atomicAdd(&sums[col], s);
            atomicAdd(&sums[DH + col], s2);
        }
    }
}

// ---------------- BatchNorm passes ----------------

__global__ void finalize_k(const float* __restrict__ sums, const float* __restrict__ g,
                           const float* __restrict__ b, float* __restrict__ ac){
    int c = blockIdx.x*256 + threadIdx.x;
    if (c < DH){
        float mu  = sums[c] * (1.f/NN);
        float var = sums[DH + c] * (1.f/NN) - mu*mu;
        var = fmaxf(var, 0.f);
        float a = g[c] * rsqrtf(var + EPSB);
        ac[c]      = a;
        ac[DH + c] = fmaf(-mu, a, b[c]);
    }
}

__global__ void bnrelu_k(float* __restrict__ buf, int M, const float* __restrict__ ac,
                         float* __restrict__ sums2){
    int col = blockIdx.x*256 + threadIdx.x;
    int r0 = blockIdx.y*512;
    int r1 = min(r0 + 512, M);
    float a = ac[col], c = ac[DH + col];
    float s = 0.f, s2 = 0.f;
    for (int r = r0; r < r1; r++){
        long idx = (long)r*DH + col;
        float y = fmaxf(fmaf(a, buf[idx], c), 0.f);
        buf[idx] = y;
        s += y; s2 = fmaf(y, y, s2);
    }
    atomicAdd(&sums2[col], s);
    atomicAdd(&sums2[DH + col], s2);
}

__global__ void bn2write_k(const float* __restrict__ buf, const float* __restrict__ ac,
                           float* __restrict__ out, ushortT* __restrict__ hbf, int layer){
    long i = (long)blockIdx.x*256 + threadIdx.x;
    if (i < (long)NN*DH){
        int r = (int)(i >> 9);
        int c = (int)(i & 511);
        float h = fmaf(ac[c], buf[i], ac[DH + c]);
        out[(long)r*(3*DH) + layer*DH + c] = h;
        hbf[i] = f2bf(h);
    }
}

// ---------------- driver ----------------

extern "C" void kernel_launch(void* const* d_in, const int* in_sizes, int n_in,
                              void* d_out, int out_size, void* d_ws, size_t ws_size,
                              hipStream_t stream){
    const float* x0  = (const float*)d_in[0];
    const int*   src = (const int*)d_in[1];
    const int*   dst = (const int*)d_in[2];
    const int*   rel = (const int*)d_in[3];
    const float* lin_w[3]  = {(const float*)d_in[4],  (const float*)d_in[12], (const float*)d_in[20]};
    const float* self_w[3] = {(const float*)d_in[5],  (const float*)d_in[13], (const float*)d_in[21]};
    const float* lin_b[3]  = {(const float*)d_in[6],  (const float*)d_in[14], (const float*)d_in[22]};
    const float* self_b[3] = {(const float*)d_in[7],  (const float*)d_in[15], (const float*)d_in[23]};
    const float* bn1_g[3]  = {(const float*)d_in[8],  (const float*)d_in[16], (const float*)d_in[24]};
    const float* bn1_b[3]  = {(const float*)d_in[9],  (const float*)d_in[17], (const float*)d_in[25]};
    const float* bn2_g[3]  = {(const float*)d_in[10], (const float*)d_in[18], (const float*)d_in[26]};
    const float* bn2_b[3]  = {(const float*)d_in[11], (const float*)d_in[19], (const float*)d_in[27]};

    char* ws = (char*)d_ws;
    size_t off = 0;
    auto alloc = [&](size_t bytes)->char*{ char* p = ws + off; off = align256(off + bytes); return p; };

    int*     counts     = (int*)alloc((size_t)NSEG*4);
    int*     cursor     = (int*)alloc((size_t)NSEG*4);
    int*     seg_start  = (int*)alloc((size_t)(NSEG+1)*4);
    int*     bsum       = (int*)alloc(1024*4);
    int*     src_sorted = (int*)alloc((size_t)NE*4);
    float*   stats      = (float*)alloc((size_t)8*DH*4);
    float*   sums1 = stats;            float* sums2 = stats + 2*DH;
    float*   ac1   = stats + 4*DH;     float* ac2   = stats + 6*DH;
    float*   outbuf = (float*)alloc((size_t)NN*DH*4);
    ushortT* hbf    = (ushortT*)alloc((size_t)NN*DH*2);
    ushortT* Wcat   = (ushortT*)alloc((size_t)DH*4096*2);
    ushortT* Acat0  = (ushortT*)alloc((size_t)NN*192*2);

    // Acat (bf16, M x 4096) gets the remainder; chunk nodes if it can't hold all.
    size_t remain = (ws_size > off) ? (ws_size - off) : 0;
    long max_nodes = (long)(remain / ((size_t)4096*2));
    int chunk = (int)((max_nodes > NN) ? NN : max_nodes);
    chunk &= ~127;
    if (chunk < 128) chunk = 128;
    ushortT* Acat = (ushortT*)(ws + off);

    // CSR build (graph is layer-invariant)
    hipMemsetAsync(counts, 0, (size_t)NSEG*4, stream);
    hipMemsetAsync(cursor, 0, (size_t)NSEG*4, stream);
    hist_k<<<(NE+255)/256, 256, 0, stream>>>(dst, rel, counts);
    int nb = (NSEG + 1023)/1024;
    scan1_k<<<nb, 256, 0, stream>>>(counts, bsum);
    scan2_k<<<1, 256, 0, stream>>>(bsum, nb, seg_start);
    scan3_k<<<nb, 256, 0, stream>>>(counts, bsum, seg_start);
    scatter_k<<<(NE+255)/256, 256, 0, stream>>>(src, dst, rel, seg_start, cursor, src_sorted);

    const int MB = (NN + 127)/128;   // 235 row panels

    for (int layer = 0; layer < 3; layer++){
        int d  = (layer == 0) ? DIN : DH;
        int Kp = (layer == 0) ? 192 : 8*DH;
        convw_k<<<(DH*Kp + 255)/256, 256, 0, stream>>>(lin_w[layer], self_w[layer], d, Kp, Wcat);
        hipMemsetAsync(stats, 0, (size_t)4*DH*4, stream);   // sums1 + sums2

        if (layer == 0){
            segsum21b_k<<<NN, 64, 0, stream>>>(x0, seg_start, src_sorted, Acat0);
            gemm_mfma_k<<<dim3(4, MB), 256, 0, stream>>>(
                Acat0, Kp, NN, Wcat, lin_b[layer], self_b[layer], outbuf, Kp/BK, sums1);
        } else {
            for (int c0 = 0; c0 < NN; c0 += chunk){
                int cn = (NN - c0 < chunk) ? (NN - c0) : chunk;
                segsum_wave_k<<<(cn + 3)/4, 256, 0, stream>>>(
                    hbf, seg_start, src_sorted, Acat, c0, cn);
                gemm_mfma_k<<<dim3(4, (cn + 127)/128), 256, 0, stream>>>(
                    Acat, Kp, cn, Wcat, lin_b[layer], self_b[layer],
                    outbuf + (long)c0*DH, Kp/BK, sums1);
            }
        }

        finalize_k<<<2, 256, 0, stream>>>(sums1, bn1_g[layer], bn1_b[layer], ac1);
        bnrelu_k<<<dim3(2, (NN+511)/512), 256, 0, stream>>>(outbuf, NN, ac1, sums2);
        finalize_k<<<2, 256, 0, stream>>>(sums2, bn2_g[layer], bn2_b[layer], ac2);
        bn2write_k<<<((long)NN*DH + 255)/256, 256, 0, stream>>>(outbuf, ac2, (float*)d_out, hbf, layer);
    }
}

// Round 6
// 972.047 us; speedup vs baseline: 1.7880x; 1.6602x over previous
//
#include <hip/hip_runtime.h>

#define NN   30000
#define NE   480000
#define NR   7
#define NSEG (NN*NR)
#define DH   512
#define DIN  21
#define EPSB 1e-5f
#define BK   32
#define KSEG 3584          // 7*512 gathered columns (self handled from hbf)
#define CHMAX 15360        // chunk rows (multiple of 128), ~110 MB Acat -> L3-resident

typedef __attribute__((ext_vector_type(8))) short bf16x8;
typedef __attribute__((ext_vector_type(8))) unsigned short u16x8;
typedef __attribute__((ext_vector_type(4))) float f32x4;
typedef unsigned short ushortT;

static inline size_t align256(size_t x){ return (x + 255) & ~(size_t)255; }

__device__ inline float bf2f(ushortT u){
    unsigned int i = ((unsigned int)u) << 16; float f; __builtin_memcpy(&f, &i, 4); return f;
}
__device__ inline ushortT f2bf(float f){
    unsigned int i; __builtin_memcpy(&i, &f, 4);
    unsigned int r = i + 0x7FFFu + ((i >> 16) & 1u);
    return (ushortT)(r >> 16);
}

__device__ inline void load_lds16(const ushortT* g, ushortT* l){
    __builtin_amdgcn_global_load_lds((const __attribute__((address_space(1))) unsigned int*)g,
                                     (__attribute__((address_space(3))) unsigned int*)l,
                                     16, 0, 0);
}

// ---------------- CSR build (counting sort by seg = dst*7+rel) ----------------

__global__ void hist_k(const int* __restrict__ dst, const int* __restrict__ rel,
                       int* __restrict__ counts){
    int e = blockIdx.x*256 + threadIdx.x;
    if (e < NE) atomicAdd(&counts[dst[e]*NR + rel[e]], 1);
}

__global__ void scan1_k(const int* __restrict__ counts, int* __restrict__ bsum){
    __shared__ int sd[256];
    int t = threadIdx.x;
    int base = blockIdx.x*1024 + t*4;
    int s = 0;
#pragma unroll
    for (int i = 0; i < 4; i++){ int idx = base + i; if (idx < NSEG) s += counts[idx]; }
    sd[t] = s; __syncthreads();
    for (int off = 128; off > 0; off >>= 1){
        if (t < off) sd[t] += sd[t+off];
        __syncthreads();
    }
    if (t == 0) bsum[blockIdx.x] = sd[0];
}

__global__ void scan2_k(int* __restrict__ bsum, int nb, int* __restrict__ seg_start){
    __shared__ int sd[256];
    int t = threadIdx.x;
    int v = (t < nb) ? bsum[t] : 0;
    sd[t] = v; __syncthreads();
    for (int off = 1; off < 256; off <<= 1){
        int x = sd[t];
        if (t >= off) x += sd[t-off];
        __syncthreads();
        sd[t] = x; __syncthreads();
    }
    if (t < nb) bsum[t] = (t == 0) ? 0 : sd[t-1];
    if (t == 0) seg_start[NSEG] = NE;
}

__global__ void scan3_k(const int* __restrict__ counts, const int* __restrict__ bsum,
                        int* __restrict__ seg_start){
    __shared__ int sd[256];
    int t = threadIdx.x;
    int base = blockIdx.x*1024 + t*4;
    int v[4]; int s = 0;
#pragma unroll
    for (int i = 0; i < 4; i++){ int idx = base + i; v[i] = (idx < NSEG) ? counts[idx] : 0; s += v[i]; }
    sd[t] = s; __syncthreads();
    for (int off = 1; off < 256; off <<= 1){
        int x = sd[t];
        if (t >= off) x += sd[t-off];
        __syncthreads();
        sd[t] = x; __syncthreads();
    }
    int excl = sd[t] - s + bsum[blockIdx.x];
#pragma unroll
    for (int i = 0; i < 4; i++){
        int idx = base + i;
        if (idx < NSEG){ seg_start[idx] = excl; excl += v[i]; }
    }
}

__global__ void scatter_k(const int* __restrict__ src, const int* __restrict__ dst,
                          const int* __restrict__ rel, const int* __restrict__ seg_start,
                          int* __restrict__ cursor, int* __restrict__ src_sorted){
    int e = blockIdx.x*256 + threadIdx.x;
    if (e < NE){
        int s = dst[e]*NR + rel[e];
        int pos = seg_start[s] + atomicAdd(&cursor[s], 1);
        src_sorted[pos] = src[e];
    }
}

// ---------------- layer 0: segment sum d=21, Kp=192 (147 upd | 21 self | 24 pad) ----------------

__global__ void segsum21b_k(const float* __restrict__ x0,
                            const int* __restrict__ seg_start, const int* __restrict__ src_sorted,
                            ushortT* __restrict__ Acat){
    int n = blockIdx.x;
    int t = threadIdx.x;   // 64
    ushortT* arow = Acat + (long)n*192;
    if (t < DIN){
        int sb = n*NR;
        int e0 = seg_start[sb];
#pragma unroll
        for (int r = 0; r < NR; r++){
            int e1 = seg_start[sb + r + 1];
            float a = 0.f;
            for (int e = e0; e < e1; e++) a += x0[(long)src_sorted[e]*DIN + t];
            e0 = e1;
            arow[r*DIN + t] = f2bf(a);
        }
        arow[7*DIN + t] = f2bf(x0[(long)n*DIN + t]);
    }
    if (t >= 40) arow[168 + (t - 40)] = 0;   // zero pad cols 168..191
}

// ---------------- layers 1,2: one WAVE per node, 7-rel segment sum → Acat[*,3584] ----------------
// 64 lanes x ushort8 = full 512-col row per load; edge loop wave-uniform; 2-way unrolled (MLP).

__global__ __launch_bounds__(256)
void segsum_wave_k(const ushortT* __restrict__ hbf,
                   const int* __restrict__ seg_start, const int* __restrict__ src_sorted,
                   ushortT* __restrict__ Acat, int c0, int cn){
    int wid = (blockIdx.x*256 + threadIdx.x) >> 6;
    if (wid >= cn) return;
    const int n = c0 + wid;
    const int lane = (threadIdx.x & 63);
    const int co = lane*8;

    int sb[8];
#pragma unroll
    for (int i = 0; i < 8; i++) sb[i] = seg_start[n*NR + i];

    ushortT* arow = Acat + (long)wid*KSEG + co;
#pragma unroll
    for (int r = 0; r < NR; r++){
        float a[8];
#pragma unroll
        for (int j = 0; j < 8; j++) a[j] = 0.f;
        int e = sb[r], e1 = sb[r+1];
        for (; e + 1 < e1; e += 2){
            u16x8 v0 = *reinterpret_cast<const u16x8*>(hbf + (long)src_sorted[e]*DH + co);
            u16x8 v1 = *reinterpret_cast<const u16x8*>(hbf + (long)src_sorted[e+1]*DH + co);
#pragma unroll
            for (int j = 0; j < 8; j++) a[j] += bf2f((ushortT)v0[j]) + bf2f((ushortT)v1[j]);
        }
        if (e < e1){
            u16x8 v = *reinterpret_cast<const u16x8*>(hbf + (long)src_sorted[e]*DH + co);
#pragma unroll
            for (int j = 0; j < 8; j++) a[j] += bf2f((ushortT)v[j]);
        }
        u16x8 o;
#pragma unroll
        for (int j = 0; j < 8; j++) o[j] = f2bf(a[j]);
        *reinterpret_cast<u16x8*>(arow + r*DH) = o;
    }
}

// ---------------- weight concat + bf16 convert: Wcat[512][Kp] ----------------

__global__ void convw_k(const float* __restrict__ lw, const float* __restrict__ sw,
                        int d, int Kp, ushortT* __restrict__ Wc){
    int i = blockIdx.x*256 + threadIdx.x;
    if (i < DH*Kp){
        int n = i / Kp, k = i % Kp;
        float v;
        if (k < 7*d)      v = lw[(long)n*7*d + k];
        else if (k < 8*d) v = sw[(long)n*d + (k - 7*d)];
        else              v = 0.f;
        Wc[i] = f2bf(v);
    }
}

// ---------------- MFMA GEMM (128x128 tile, 4 waves) + fused col-stats ----------------
// A-tiles kt<ntA come from A (lda); kt>=ntA come from hbase (ld 512, the self-loop block).
// grid = (N-tiles fastest, M-panels).

__global__ __launch_bounds__(256)
void gemm_mfma_k(const ushortT* __restrict__ A, int lda, int ntA,
                 const ushortT* __restrict__ hbase, int M,
                 const ushortT* __restrict__ W, int ldw,
                 const float* __restrict__ b1, const float* __restrict__ b2,
                 float* __restrict__ C, int nt, float* __restrict__ sums){
    __shared__ ushortT As[2][128*BK];
    __shared__ ushortT Bs[2][128*BK];
    const int t    = threadIdx.x;
    const int bm   = blockIdx.y*128;
    const int bn   = blockIdx.x*128;
    const int w    = t >> 6;
    const int lane = t & 63;

    int f0 = w*128 + lane, f1 = f0 + 64;
    const int ar0 = min(bm + (f0 >> 2), M-1), ac0 = (f0 & 3)*8;
    const int ar1 = min(bm + (f1 >> 2), M-1), ac1 = (f1 & 3)*8;
    const int br0 = bn + (f0 >> 2), br1 = bn + (f1 >> 2);
    const int d0 = (w*128 +  0)*8;
    const int d1 = (w*128 + 64)*8;

    f32x4 acc[4][4];
#pragma unroll
    for (int m = 0; m < 4; m++)
#pragma unroll
        for (int n = 0; n < 4; n++) acc[m][n] = (f32x4){0.f,0.f,0.f,0.f};

    const int wm = w >> 1, wn = w & 1;
    const int r = lane & 15, hi = lane >> 4;

    auto stage = [&](int kt, int b){
        const ushortT* p0;
        const ushortT* p1;
        if (kt < ntA){
            p0 = A + (long)ar0*lda + kt*BK + ac0;
            p1 = A + (long)ar1*lda + kt*BK + ac1;
        } else {
            int k0 = (kt - ntA)*BK;
            p0 = hbase + (long)ar0*DH + k0 + ac0;
            p1 = hbase + (long)ar1*DH + k0 + ac1;
        }
        load_lds16(p0, &As[b][d0]);
        load_lds16(p1, &As[b][d1]);
        load_lds16(W + (long)br0*ldw + kt*BK + ac0, &Bs[b][d0]);
        load_lds16(W + (long)br1*ldw + kt*BK + ac1, &Bs[b][d1]);
    };

    stage(0, 0);

    for (int kt = 0; kt < nt; ++kt){
        __syncthreads();
        if (kt + 1 < nt) stage(kt + 1, (kt + 1) & 1);
        int buf = kt & 1;
        bf16x8 af[4], bfr[4];
#pragma unroll
        for (int m = 0; m < 4; m++)
            af[m] = *reinterpret_cast<const bf16x8*>(&As[buf][(wm*64 + m*16 + r)*BK + hi*8]);
#pragma unroll
        for (int n = 0; n < 4; n++)
            bfr[n] = *reinterpret_cast<const bf16x8*>(&Bs[buf][(wn*64 + n*16 + r)*BK + hi*8]);
#pragma unroll
        for (int m = 0; m < 4; m++)
#pragma unroll
            for (int n = 0; n < 4; n++)
                acc[m][n] = __builtin_amdgcn_mfma_f32_16x16x32_bf16(af[m], bfr[n], acc[m][n], 0, 0, 0);
    }

#pragma unroll
    for (int n = 0; n < 4; n++){
        int col = bn + wn*64 + n*16 + r;
        float bb = b1[col] + b2[col];
        float s = 0.f, s2 = 0.f;
#pragma unroll
        for (int m = 0; m < 4; m++){
            int row = bm + wm*64 + m*16 + hi*4;
#pragma unroll
            for (int q = 0; q < 4; q++){
                if (row + q < M){
                    float v = acc[m][n][q] + bb;
                    C[(long)(row + q)*DH + col] = v;
                    s += v; s2 = fmaf(v, v, s2);
                }
            }
        }
        s  += __shfl_xor(s, 16);  s  += __shfl_xor(s, 32);
        s2 += __shfl_xor(s2, 16); s2 += __shfl_xor(s2, 32);
        if (hi == 0){
            atomicAdd(&sums[col], s);
            atomicAdd(&sums[DH + col], s2);
        }
    }
}

// ---------------- BatchNorm passes ----------------

__global__ void finalize_k(const float* __restrict__ sums, const float* __restrict__ g,
                           const float* __restrict__ b, float* __restrict__ ac){
    int c = blockIdx.x*256 + threadIdx.x;
    if (c < DH){
        float mu  = sums[c] * (1.f/NN);
        float var = sums[DH + c] * (1.f/NN) - mu*mu;
        var = fmaxf(var, 0.f);
        float a = g[c] * rsqrtf(var + EPSB);
        ac[c]      = a;
        ac[DH + c] = fmaf(-mu, a, b[c]);
    }
}

__global__ void bnrelu_k(float* __restrict__ buf, int M, const float* __restrict__ ac,
                         float* __restrict__ sums2){
    int col = blockIdx.x*256 + threadIdx.x;
    int r0 = blockIdx.y*128;
    int r1 = min(r0 + 128, M);
    float a = ac[col], c = ac[DH + col];
    float s = 0.f, s2 = 0.f;
    for (int r = r0; r < r1; r++){
        long idx = (long)r*DH + col;
        float y = fmaxf(fmaf(a, buf[idx], c), 0.f);
        buf[idx] = y;
        s += y; s2 = fmaf(y, y, s2);
    }
    atomicAdd(&sums2[col], s);
    atomicAdd(&sums2[DH + col], s2);
}

__global__ void bn2write_k(const float* __restrict__ buf, const float* __restrict__ ac,
                           float* __restrict__ out, ushortT* __restrict__ hbf, int layer){
    long i = (long)blockIdx.x*256 + threadIdx.x;
    if (i < (long)NN*DH){
        int r = (int)(i >> 9);
        int c = (int)(i & 511);
        float h = fmaf(ac[c], buf[i], ac[DH + c]);
        out[(long)r*(3*DH) + layer*DH + c] = h;
        hbf[i] = f2bf(h);
    }
}

// ---------------- driver ----------------

extern "C" void kernel_launch(void* const* d_in, const int* in_sizes, int n_in,
                              void* d_out, int out_size, void* d_ws, size_t ws_size,
                              hipStream_t stream){
    const float* x0  = (const float*)d_in[0];
    const int*   src = (const int*)d_in[1];
    const int*   dst = (const int*)d_in[2];
    const int*   rel = (const int*)d_in[3];
    const float* lin_w[3]  = {(const float*)d_in[4],  (const float*)d_in[12], (const float*)d_in[20]};
    const float* self_w[3] = {(const float*)d_in[5],  (const float*)d_in[13], (const float*)d_in[21]};
    const float* lin_b[3]  = {(const float*)d_in[6],  (const float*)d_in[14], (const float*)d_in[22]};
    const float* self_b[3] = {(const float*)d_in[7],  (const float*)d_in[15], (const float*)d_in[23]};
    const float* bn1_g[3]  = {(const float*)d_in[8],  (const float*)d_in[16], (const float*)d_in[24]};
    const float* bn1_b[3]  = {(const float*)d_in[9],  (const float*)d_in[17], (const float*)d_in[25]};
    const float* bn2_g[3]  = {(const float*)d_in[10], (const float*)d_in[18], (const float*)d_in[26]};
    const float* bn2_b[3]  = {(const float*)d_in[11], (const float*)d_in[19], (const float*)d_in[27]};

    char* ws = (char*)d_ws;
    size_t off = 0;
    auto alloc = [&](size_t bytes)->char*{ char* p = ws + off; off = align256(off + bytes); return p; };

    int*     counts     = (int*)alloc((size_t)NSEG*4);
    int*     cursor     = (int*)alloc((size_t)NSEG*4);
    int*     seg_start  = (int*)alloc((size_t)(NSEG+1)*4);
    int*     bsum       = (int*)alloc(1024*4);
    int*     src_sorted = (int*)alloc((size_t)NE*4);
    float*   stats      = (float*)alloc((size_t)8*DH*4);
    float*   sums1 = stats;            float* sums2 = stats + 2*DH;
    float*   ac1   = stats + 4*DH;     float* ac2   = stats + 6*DH;
    float*   outbuf = (float*)alloc((size_t)NN*DH*4);
    ushortT* hbf    = (ushortT*)alloc((size_t)NN*DH*2);
    ushortT* Wcat   = (ushortT*)alloc((size_t)DH*4096*2);
    ushortT* Acat0  = (ushortT*)alloc((size_t)NN*192*2);

    // Acat (bf16, chunk x 3584) gets the remainder; chunk kept <= CHMAX for L3 residency.
    size_t remain = (ws_size > off) ? (ws_size - off) : 0;
    long max_nodes = (long)(remain / ((size_t)KSEG*2));
    int chunk = (int)((max_nodes > CHMAX) ? CHMAX : max_nodes);
    chunk &= ~127;
    if (chunk < 128) chunk = 128;
    ushortT* Acat = (ushortT*)(ws + off);

    // CSR build (graph is layer-invariant)
    hipMemsetAsync(counts, 0, (size_t)NSEG*4, stream);
    hipMemsetAsync(cursor, 0, (size_t)NSEG*4, stream);
    hist_k<<<(NE+255)/256, 256, 0, stream>>>(dst, rel, counts);
    int nb = (NSEG + 1023)/1024;
    scan1_k<<<nb, 256, 0, stream>>>(counts, bsum);
    scan2_k<<<1, 256, 0, stream>>>(bsum, nb, seg_start);
    scan3_k<<<nb, 256, 0, stream>>>(counts, bsum, seg_start);
    scatter_k<<<(NE+255)/256, 256, 0, stream>>>(src, dst, rel, seg_start, cursor, src_sorted);

    const int MB = (NN + 127)/128;   // 235 row panels

    for (int layer = 0; layer < 3; layer++){
        int d  = (layer == 0) ? DIN : DH;
        int Kp = (layer == 0) ? 192 : 8*DH;
        convw_k<<<(DH*Kp + 255)/256, 256, 0, stream>>>(lin_w[layer], self_w[layer], d, Kp, Wcat);
        hipMemsetAsync(stats, 0, (size_t)4*DH*4, stream);   // sums1 + sums2

        if (layer == 0){
            segsum21b_k<<<NN, 64, 0, stream>>>(x0, seg_start, src_sorted, Acat0);
            gemm_mfma_k<<<dim3(4, MB), 256, 0, stream>>>(
                Acat0, 192, 6, Acat0, NN, Wcat, 192,
                lin_b[layer], self_b[layer], outbuf, 6, sums1);
        } else {
            for (int c0 = 0; c0 < NN; c0 += chunk){
                int cn = (NN - c0 < chunk) ? (NN - c0) : chunk;
                segsum_wave_k<<<(cn + 3)/4, 256, 0, stream>>>(
                    hbf, seg_start, src_sorted, Acat, c0, cn);
                gemm_mfma_k<<<dim3(4, (cn + 127)/128), 256, 0, stream>>>(
                    Acat, KSEG, 112, hbf + (long)c0*DH, cn, Wcat, 4096,
                    lin_b[layer], self_b[layer],
                    outbuf + (long)c0*DH, 128, sums1);
            }
        }

        finalize_k<<<2, 256, 0, stream>>>(sums1, bn1_g[layer], bn1_b[layer], ac1);
        bnrelu_k<<<dim3(2, (NN+127)/128), 256, 0, stream>>>(outbuf, NN, ac1, sums2);
        finalize_k<<<2, 256, 0, stream>>>(sums2, bn2_g[layer], bn2_b[layer], ac2);
        bn2write_k<<<((long)NN*DH + 255)/256, 256, 0, stream>>>(outbuf, ac2, (float*)d_out, hbf, layer);
    }
}

// Round 7
// 959.517 us; speedup vs baseline: 1.8114x; 1.0131x over previous
//
#include <hip/hip_runtime.h>

#define NN   30000
#define NE   480000
#define NR   7
#define NSEG (NN*NR)
#define DH   512
#define DIN  21
#define EPSB 1e-5f
#define BK   32
#define KSEG 3584          // 7*512 gathered columns (self handled from hbf)
#define CHMAX 15360        // chunk rows (multiple of 128), ~110 MB Acat -> L3-resident

typedef __attribute__((ext_vector_type(8))) short bf16x8;
typedef __attribute__((ext_vector_type(8))) unsigned short u16x8;
typedef __attribute__((ext_vector_type(4))) float f32x4;
typedef unsigned short ushortT;

static inline size_t align256(size_t x){ return (x + 255) & ~(size_t)255; }

__device__ inline float bf2f(ushortT u){
    unsigned int i = ((unsigned int)u) << 16; float f; __builtin_memcpy(&f, &i, 4); return f;
}
__device__ inline ushortT f2bf(float f){
    unsigned int i; __builtin_memcpy(&i, &f, 4);
    unsigned int r = i + 0x7FFFu + ((i >> 16) & 1u);
    return (ushortT)(r >> 16);
}

__device__ inline void load_lds16(const ushortT* g, ushortT* l){
    __builtin_amdgcn_global_load_lds((const __attribute__((address_space(1))) unsigned int*)g,
                                     (__attribute__((address_space(3))) unsigned int*)l,
                                     16, 0, 0);
}

// ---------------- CSR build (counting sort by seg = dst*7+rel) ----------------

__global__ void hist_k(const int* __restrict__ dst, const int* __restrict__ rel,
                       int* __restrict__ counts){
    int e = blockIdx.x*256 + threadIdx.x;
    if (e < NE) atomicAdd(&counts[dst[e]*NR + rel[e]], 1);
}

__global__ void scan1_k(const int* __restrict__ counts, int* __restrict__ bsum){
    __shared__ int sd[256];
    int t = threadIdx.x;
    int base = blockIdx.x*1024 + t*4;
    int s = 0;
#pragma unroll
    for (int i = 0; i < 4; i++){ int idx = base + i; if (idx < NSEG) s += counts[idx]; }
    sd[t] = s; __syncthreads();
    for (int off = 128; off > 0; off >>= 1){
        if (t < off) sd[t] += sd[t+off];
        __syncthreads();
    }
    if (t == 0) bsum[blockIdx.x] = sd[0];
}

__global__ void scan2_k(int* __restrict__ bsum, int nb, int* __restrict__ seg_start){
    __shared__ int sd[256];
    int t = threadIdx.x;
    int v = (t < nb) ? bsum[t] : 0;
    sd[t] = v; __syncthreads();
    for (int off = 1; off < 256; off <<= 1){
        int x = sd[t];
        if (t >= off) x += sd[t-off];
        __syncthreads();
        sd[t] = x; __syncthreads();
    }
    if (t < nb) bsum[t] = (t == 0) ? 0 : sd[t-1];
    if (t == 0) seg_start[NSEG] = NE;
}

__global__ void scan3_k(const int* __restrict__ counts, const int* __restrict__ bsum,
                        int* __restrict__ seg_start){
    __shared__ int sd[256];
    int t = threadIdx.x;
    int base = blockIdx.x*1024 + t*4;
    int v[4]; int s = 0;
#pragma unroll
    for (int i = 0; i < 4; i++){ int idx = base + i; v[i] = (idx < NSEG) ? counts[idx] : 0; s += v[i]; }
    sd[t] = s; __syncthreads();
    for (int off = 1; off < 256; off <<= 1){
        int x = sd[t];
        if (t >= off) x += sd[t-off];
        __syncthreads();
        sd[t] = x; __syncthreads();
    }
    int excl = sd[t] - s + bsum[blockIdx.x];
#pragma unroll
    for (int i = 0; i < 4; i++){
        int idx = base + i;
        if (idx < NSEG){ seg_start[idx] = excl; excl += v[i]; }
    }
}

__global__ void scatter_k(const int* __restrict__ src, const int* __restrict__ dst,
                          const int* __restrict__ rel, const int* __restrict__ seg_start,
                          int* __restrict__ cursor, int* __restrict__ src_sorted){
    int e = blockIdx.x*256 + threadIdx.x;
    if (e < NE){
        int s = dst[e]*NR + rel[e];
        int pos = seg_start[s] + atomicAdd(&cursor[s], 1);
        src_sorted[pos] = src[e];
    }
}

// ---------------- layer 0: segment sum d=21, Kp=192 (147 upd | 21 self | 24 pad) ----------------

__global__ void segsum21b_k(const float* __restrict__ x0,
                            const int* __restrict__ seg_start, const int* __restrict__ src_sorted,
                            ushortT* __restrict__ Acat){
    int n = blockIdx.x;
    int t = threadIdx.x;   // 64
    ushortT* arow = Acat + (long)n*192;
    if (t < DIN){
        int sb = n*NR;
        int e0 = seg_start[sb];
#pragma unroll
        for (int r = 0; r < NR; r++){
            int e1 = seg_start[sb + r + 1];
            float a = 0.f;
            for (int e = e0; e < e1; e++) a += x0[(long)src_sorted[e]*DIN + t];
            e0 = e1;
            arow[r*DIN + t] = f2bf(a);
        }
        arow[7*DIN + t] = f2bf(x0[(long)n*DIN + t]);
    }
    if (t >= 40) arow[168 + (t - 40)] = 0;   // zero pad cols 168..191
}

// ---------------- layers 1,2: one WAVE per node, 7-rel segment sum → Acat[*,3584] ----------------

__global__ __launch_bounds__(256)
void segsum_wave_k(const ushortT* __restrict__ hbf,
                   const int* __restrict__ seg_start, const int* __restrict__ src_sorted,
                   ushortT* __restrict__ Acat, int c0, int cn){
    int wid = (blockIdx.x*256 + threadIdx.x) >> 6;
    if (wid >= cn) return;
    const int n = c0 + wid;
    const int lane = (threadIdx.x & 63);
    const int co = lane*8;

    int sb[8];
#pragma unroll
    for (int i = 0; i < 8; i++) sb[i] = seg_start[n*NR + i];

    ushortT* arow = Acat + (long)wid*KSEG + co;
#pragma unroll
    for (int r = 0; r < NR; r++){
        float a[8];
#pragma unroll
        for (int j = 0; j < 8; j++) a[j] = 0.f;
        int e = sb[r], e1 = sb[r+1];
        for (; e + 1 < e1; e += 2){
            u16x8 v0 = *reinterpret_cast<const u16x8*>(hbf + (long)src_sorted[e]*DH + co);
            u16x8 v1 = *reinterpret_cast<const u16x8*>(hbf + (long)src_sorted[e+1]*DH + co);
#pragma unroll
            for (int j = 0; j < 8; j++) a[j] += bf2f((ushortT)v0[j]) + bf2f((ushortT)v1[j]);
        }
        if (e < e1){
            u16x8 v = *reinterpret_cast<const u16x8*>(hbf + (long)src_sorted[e]*DH + co);
#pragma unroll
            for (int j = 0; j < 8; j++) a[j] += bf2f((ushortT)v[j]);
        }
        u16x8 o;
#pragma unroll
        for (int j = 0; j < 8; j++) o[j] = f2bf(a[j]);
        *reinterpret_cast<u16x8*>(arow + r*DH) = o;
    }
}

// ---------------- weight concat + bf16 convert: Wcat[512][Kp] ----------------

__global__ void convw_k(const float* __restrict__ lw, const float* __restrict__ sw,
                        int d, int Kp, ushortT* __restrict__ Wc){
    int i = blockIdx.x*256 + threadIdx.x;
    if (i < DH*Kp){
        int n = i / Kp, k = i % Kp;
        float v;
        if (k < 7*d)      v = lw[(long)n*7*d + k];
        else if (k < 8*d) v = sw[(long)n*d + (k - 7*d)];
        else              v = 0.f;
        Wc[i] = f2bf(v);
    }
}

// ---------------- MFMA GEMM (128x128 tile, 4 waves) + fused col-stats ----------------
// 1-D grid, bijective XCD swizzle: each XCD gets a contiguous logical range so all
// 4 N-tiles of a panel share one XCD's L2 (A fetched ~once from HBM).
// 3-deep LDS pipeline with counted vmcnt + raw barrier: loads get ~2 K-steps lead.

__global__ __launch_bounds__(256)
void gemm_mfma_k(const ushortT* __restrict__ A, int lda, int ntA,
                 const ushortT* __restrict__ hbase, int M,
                 const ushortT* __restrict__ W, int ldw,
                 const float* __restrict__ b1, const float* __restrict__ b2,
                 float* __restrict__ C, int nt, float* __restrict__ sums){
    __shared__ ushortT As[3][128*BK];
    __shared__ ushortT Bs[3][128*BK];
    const int t    = threadIdx.x;

    // XCD panel-affinity swizzle (bijective, m204)
    const int nwg = gridDim.x;
    int q = nwg >> 3, rmd = nwg & 7;
    int xcd = blockIdx.x & 7, slot = blockIdx.x >> 3;
    int l = xcd*q + min(xcd, rmd) + slot;
    const int bm = (l >> 2)*128;
    const int bn = (l & 3)*128;

    const int w    = t >> 6;
    const int lane = t & 63;

    int f0 = w*128 + lane, f1 = f0 + 64;
    const int ar0 = min(bm + (f0 >> 2), M-1), ac0 = (f0 & 3)*8;
    const int ar1 = min(bm + (f1 >> 2), M-1), ac1 = (f1 & 3)*8;
    const int br0 = bn + (f0 >> 2), br1 = bn + (f1 >> 2);
    const int d0 = (w*128 +  0)*8;
    const int d1 = (w*128 + 64)*8;

    f32x4 acc[4][4];
#pragma unroll
    for (int m = 0; m < 4; m++)
#pragma unroll
        for (int n = 0; n < 4; n++) acc[m][n] = (f32x4){0.f,0.f,0.f,0.f};

    const int wm = w >> 1, wn = w & 1;
    const int r = lane & 15, hi = lane >> 4;

    auto stage = [&](int kt, int b){
        const ushortT* p0;
        const ushortT* p1;
        if (kt < ntA){
            p0 = A + (long)ar0*lda + kt*BK + ac0;
            p1 = A + (long)ar1*lda + kt*BK + ac1;
        } else {
            int k0 = (kt - ntA)*BK;
            p0 = hbase + (long)ar0*DH + k0 + ac0;
            p1 = hbase + (long)ar1*DH + k0 + ac1;
        }
        load_lds16(p0, &As[b][d0]);
        load_lds16(p1, &As[b][d1]);
        load_lds16(W + (long)br0*ldw + kt*BK + ac0, &Bs[b][d0]);
        load_lds16(W + (long)br1*ldw + kt*BK + ac1, &Bs[b][d1]);
    };

    // prologue: tiles 0 and 1 in flight (4 loads each per thread)
    stage(0, 0);
    stage(1, 1);

    for (int kt = 0; kt < nt; ++kt){
        // wait for tile kt (allow tile kt+1's 4 loads to remain in flight)
        if (kt + 1 < nt) asm volatile("s_waitcnt vmcnt(4)" ::: "memory");
        else             asm volatile("s_waitcnt vmcnt(0)" ::: "memory");
        __builtin_amdgcn_s_barrier();          // raw barrier: no vmcnt(0) drain
        __builtin_amdgcn_sched_barrier(0);
        if (kt + 2 < nt) stage(kt + 2, (kt + 2) % 3);
        const int buf = kt % 3;
        bf16x8 af[4], bfr[4];
#pragma unroll
        for (int m = 0; m < 4; m++)
            af[m] = *reinterpret_cast<const bf16x8*>(&As[buf][(wm*64 + m*16 + r)*BK + hi*8]);
#pragma unroll
        for (int n = 0; n < 4; n++)
            bfr[n] = *reinterpret_cast<const bf16x8*>(&Bs[buf][(wn*64 + n*16 + r)*BK + hi*8]);
#pragma unroll
        for (int m = 0; m < 4; m++)
#pragma unroll
            for (int n = 0; n < 4; n++)
                acc[m][n] = __builtin_amdgcn_mfma_f32_16x16x32_bf16(af[m], bfr[n], acc[m][n], 0, 0, 0);
    }

#pragma unroll
    for (int n = 0; n < 4; n++){
        int col = bn + wn*64 + n*16 + r;
        float bb = b1[col] + b2[col];
        float s = 0.f, s2 = 0.f;
#pragma unroll
        for (int m = 0; m < 4; m++){
            int row = bm + wm*64 + m*16 + hi*4;
#pragma unroll
            for (int q2 = 0; q2 < 4; q2++){
                if (row + q2 < M){
                    float v = acc[m][n][q2] + bb;
                    C[(long)(row + q2)*DH + col] = v;
                    s += v; s2 = fmaf(v, v, s2);
                }
            }
        }
        s  += __shfl_xor(s, 16);  s  += __shfl_xor(s, 32);
        s2 += __shfl_xor(s2, 16); s2 += __shfl_xor(s2, 32);
        if (hi == 0){
            atomicAdd(&sums[col], s);
            atomicAdd(&sums[DH + col], s2);
        }
    }
}

// ---------------- BatchNorm passes ----------------

__global__ void finalize_k(const float* __restrict__ sums, const float* __restrict__ g,
                           const float* __restrict__ b, float* __restrict__ ac){
    int c = blockIdx.x*256 + threadIdx.x;
    if (c < DH){
        float mu  = sums[c] * (1.f/NN);
        float var = sums[DH + c] * (1.f/NN) - mu*mu;
        var = fmaxf(var, 0.f);
        float a = g[c] * rsqrtf(var + EPSB);
        ac[c]      = a;
        ac[DH + c] = fmaf(-mu, a, b[c]);
    }
}

__global__ void bnrelu_k(float* __restrict__ buf, int M, const float* __restrict__ ac,
                         float* __restrict__ sums2){
    int col = blockIdx.x*256 + threadIdx.x;
    int r0 = blockIdx.y*128;
    int r1 = min(r0 + 128, M);
    float a = ac[col], c = ac[DH + col];
    float s = 0.f, s2 = 0.f;
    for (int r = r0; r < r1; r++){
        long idx = (long)r*DH + col;
        float y = fmaxf(fmaf(a, buf[idx], c), 0.f);
        buf[idx] = y;
        s += y; s2 = fmaf(y, y, s2);
    }
    atomicAdd(&sums2[col], s);
    atomicAdd(&sums2[DH + col], s2);
}

__global__ void bn2write_k(const float* __restrict__ buf, const float* __restrict__ ac,
                           float* __restrict__ out, ushortT* __restrict__ hbf, int layer){
    long i = (long)blockIdx.x*256 + threadIdx.x;
    if (i < (long)NN*DH){
        int r = (int)(i >> 9);
        int c = (int)(i & 511);
        float h = fmaf(ac[c], buf[i], ac[DH + c]);
        out[(long)r*(3*DH) + layer*DH + c] = h;
        hbf[i] = f2bf(h);
    }
}

// ---------------- driver ----------------

extern "C" void kernel_launch(void* const* d_in, const int* in_sizes, int n_in,
                              void* d_out, int out_size, void* d_ws, size_t ws_size,
                              hipStream_t stream){
    const float* x0  = (const float*)d_in[0];
    const int*   src = (const int*)d_in[1];
    const int*   dst = (const int*)d_in[2];
    const int*   rel = (const int*)d_in[3];
    const float* lin_w[3]  = {(const float*)d_in[4],  (const float*)d_in[12], (const float*)d_in[20]};
    const float* self_w[3] = {(const float*)d_in[5],  (const float*)d_in[13], (const float*)d_in[21]};
    const float* lin_b[3]  = {(const float*)d_in[6],  (const float*)d_in[14], (const float*)d_in[22]};
    const float* self_b[3] = {(const float*)d_in[7],  (const float*)d_in[15], (const float*)d_in[23]};
    const float* bn1_g[3]  = {(const float*)d_in[8],  (const float*)d_in[16], (const float*)d_in[24]};
    const float* bn1_b[3]  = {(const float*)d_in[9],  (const float*)d_in[17], (const float*)d_in[25]};
    const float* bn2_g[3]  = {(const float*)d_in[10], (const float*)d_in[18], (const float*)d_in[26]};
    const float* bn2_b[3]  = {(const float*)d_in[11], (const float*)d_in[19], (const float*)d_in[27]};

    char* ws = (char*)d_ws;
    size_t off = 0;
    auto alloc = [&](size_t bytes)->char*{ char* p = ws + off; off = align256(off + bytes); return p; };

    int*     counts     = (int*)alloc((size_t)NSEG*4);
    int*     cursor     = (int*)alloc((size_t)NSEG*4);
    int*     seg_start  = (int*)alloc((size_t)(NSEG+1)*4);
    int*     bsum       = (int*)alloc(1024*4);
    int*     src_sorted = (int*)alloc((size_t)NE*4);
    float*   stats      = (float*)alloc((size_t)8*DH*4);
    float*   sums1 = stats;            float* sums2 = stats + 2*DH;
    float*   ac1   = stats + 4*DH;     float* ac2   = stats + 6*DH;
    float*   outbuf = (float*)alloc((size_t)NN*DH*4);
    ushortT* hbf    = (ushortT*)alloc((size_t)NN*DH*2);
    ushortT* Wcat   = (ushortT*)alloc((size_t)DH*4096*2);
    ushortT* Acat0  = (ushortT*)alloc((size_t)NN*192*2);

    // Acat (bf16, chunk x 3584) gets the remainder; chunk kept <= CHMAX for L3 residency.
    size_t remain = (ws_size > off) ? (ws_size - off) : 0;
    long max_nodes = (long)(remain / ((size_t)KSEG*2));
    int chunk = (int)((max_nodes > CHMAX) ? CHMAX : max_nodes);
    chunk &= ~127;
    if (chunk < 128) chunk = 128;
    ushortT* Acat = (ushortT*)(ws + off);

    // CSR build (graph is layer-invariant)
    hipMemsetAsync(counts, 0, (size_t)NSEG*4, stream);
    hipMemsetAsync(cursor, 0, (size_t)NSEG*4, stream);
    hist_k<<<(NE+255)/256, 256, 0, stream>>>(dst, rel, counts);
    int nb = (NSEG + 1023)/1024;
    scan1_k<<<nb, 256, 0, stream>>>(counts, bsum);
    scan2_k<<<1, 256, 0, stream>>>(bsum, nb, seg_start);
    scan3_k<<<nb, 256, 0, stream>>>(counts, bsum, seg_start);
    scatter_k<<<(NE+255)/256, 256, 0, stream>>>(src, dst, rel, seg_start, cursor, src_sorted);

    const int MB = (NN + 127)/128;   // 235 row panels

    for (int layer = 0; layer < 3; layer++){
        int d  = (layer == 0) ? DIN : DH;
        int Kp = (layer == 0) ? 192 : 8*DH;
        convw_k<<<(DH*Kp + 255)/256, 256, 0, stream>>>(lin_w[layer], self_w[layer], d, Kp, Wcat);
        hipMemsetAsync(stats, 0, (size_t)4*DH*4, stream);   // sums1 + sums2

        if (layer == 0){
            segsum21b_k<<<NN, 64, 0, stream>>>(x0, seg_start, src_sorted, Acat0);
            gemm_mfma_k<<<MB*4, 256, 0, stream>>>(
                Acat0, 192, 6, Acat0, NN, Wcat, 192,
                lin_b[layer], self_b[layer], outbuf, 6, sums1);
        } else {
            for (int c0 = 0; c0 < NN; c0 += chunk){
                int cn = (NN - c0 < chunk) ? (NN - c0) : chunk;
                segsum_wave_k<<<(cn + 3)/4, 256, 0, stream>>>(
                    hbf, seg_start, src_sorted, Acat, c0, cn);
                gemm_mfma_k<<<((cn + 127)/128)*4, 256, 0, stream>>>(
                    Acat, KSEG, 112, hbf + (long)c0*DH, cn, Wcat, 4096,
                    lin_b[layer], self_b[layer],
                    outbuf + (long)c0*DH, 128, sums1);
            }
        }

        finalize_k<<<2, 256, 0, stream>>>(sums1, bn1_g[layer], bn1_b[layer], ac1);
        bnrelu_k<<<dim3(2, (NN+127)/128), 256, 0, stream>>>(outbuf, NN, ac1, sums2);
        finalize_k<<<2, 256, 0, stream>>>(sums2, bn2_g[layer], bn2_b[layer], ac2);
        bn2write_k<<<((long)NN*DH + 255)/256, 256, 0, stream>>>(outbuf, ac2, (float*)d_out, hbf, layer);
    }
}